// Round 5
// baseline (179.966 us; speedup 1.0000x reference)
//
#include <hip/hip_runtime.h>
#include <hip/hip_cooperative_groups.h>

namespace cg = cooperative_groups;

#define N   1024
#define HD  64
#define MD  32
#define BLK 256
#define WROW (2 * HD + 1)   // 129, w_msg row stride

struct Params {
    const float* pos;
    const float* feat;
    const float* w_msg1; const float* b_msg1; const float* w_pos1; const float* b_pos1;
    const float* w_feat1; const float* b_feat1;
    const float* w_msg2; const float* b_msg2; const float* w_pos2; const float* b_pos2;
    float* h0; float* A1; float* B1; float* x1; float* ms1; float* A2; float* B2;
    float* out;
};

// ---------------------------------------------------------------------------
// Pair phase: grid-stride over row-pairs (iA, iB = iA + N/2). Block = 256 thr.
// Lane mapping in main loop: jbase = tid>>5 (8 j-slots/iter), k = tid&31.
// Per lane: m = relu(A[j][k] + Bi[k] + d2*wd[k]); P_c += m * r_c  (wp folded
// at the end); msum_k accumulated per-lane (layer 1 only).
// x_out[i] = x[i] + (Σ_k wp_ck P_ck + bp_c (Sx_c - N x_ic)) / (N-1)
// ---------------------------------------------------------------------------
template<int WRITE_MS>
__device__ void pair_phase(const Params& p,
                           const float* __restrict__ xsrc,
                           const float* __restrict__ Aap,
                           const float* __restrict__ Bbp,
                           const float* __restrict__ wmsg,
                           const float* __restrict__ wpos,
                           const float* __restrict__ bpos,
                           float* __restrict__ xout,
                           float* __restrict__ msout,
                           float4* rdA, float4* rdB,
                           float (*wacc)[8], float (*msAl)[MD], float (*msBl)[MD],
                           float* SxL)
{
    const int tid  = threadIdx.x;
    const int bid  = blockIdx.x;
    const int G    = gridDim.x;
    const int wid  = tid >> 6;
    const int lane = tid & 63;
    const int k    = tid & 31;

    for (int i0 = bid; i0 < N / 2; i0 += G) {
        const int iA = i0, iB = i0 + N / 2;
        const float xiA0 = xsrc[iA * 3 + 0], xiA1 = xsrc[iA * 3 + 1], xiA2 = xsrc[iA * 3 + 2];
        const float xiB0 = xsrc[iB * 3 + 0], xiB1 = xsrc[iB * 3 + 1], xiB2 = xsrc[iB * 3 + 2];

        // ---- stage r/d2 tables for both rows; accumulate column-sum of x ----
        float sx0 = 0.f, sx1 = 0.f, sx2 = 0.f;
#pragma unroll
        for (int q = 0; q < N / BLK; q++) {
            const int j = q * BLK + tid;
            const float xj0 = xsrc[j * 3 + 0];
            const float xj1 = xsrc[j * 3 + 1];
            const float xj2 = xsrc[j * 3 + 2];
            sx0 += xj0; sx1 += xj1; sx2 += xj2;
            float r0 = xj0 - xiA0, r1 = xj1 - xiA1, r2 = xj2 - xiA2;
            rdA[j] = make_float4(r0, r1, r2, fmaf(r0, r0, fmaf(r1, r1, r2 * r2)));
            r0 = xj0 - xiB0; r1 = xj1 - xiB1; r2 = xj2 - xiB2;
            rdB[j] = make_float4(r0, r1, r2, fmaf(r0, r0, fmaf(r1, r1, r2 * r2)));
        }
#pragma unroll
        for (int off = 32; off > 0; off >>= 1) {
            sx0 += __shfl_xor(sx0, off);
            sx1 += __shfl_xor(sx1, off);
            sx2 += __shfl_xor(sx2, off);
        }
        if (lane == 0) { wacc[wid][0] = sx0; wacc[wid][1] = sx1; wacc[wid][2] = sx2; }
        __syncthreads();                       // rd tables + sx partials ready
        if (tid == 0) {
            SxL[0] = wacc[0][0] + wacc[1][0] + wacc[2][0] + wacc[3][0];
            SxL[1] = wacc[0][1] + wacc[1][1] + wacc[2][1] + wacc[3][1];
            SxL[2] = wacc[0][2] + wacc[1][2] + wacc[2][2] + wacc[3][2];
        }

        // ---- per-lane (dim-k) weights: 6 VGPRs instead of 160 ----
        const float BiA = Bbp[iA * MD + k];
        const float BiB = Bbp[iB * MD + k];
        const float wd  = wmsg[k * WROW + 2 * HD];
        const float wp0 = wpos[k], wp1 = wpos[MD + k], wp2 = wpos[2 * MD + k];

        float PA0 = 0.f, PA1 = 0.f, PA2 = 0.f;
        float PB0 = 0.f, PB1 = 0.f, PB2 = 0.f;
        float msA = 0.f, msB = 0.f;
        const int jbase = tid >> 5;            // 0..7

#pragma unroll 4
        for (int it = 0; it < N / 8; it++) {
            const int j = it * 8 + jbase;
            const float a = Aap[j * MD + k];
            const float4 fA = rdA[j];          // broadcast within 32-lane group
            const float4 fB = rdB[j];
            const float mA = fmaxf(fmaf(fA.w, wd, a + BiA), 0.f);
            const float mB = fmaxf(fmaf(fB.w, wd, a + BiB), 0.f);
            if (WRITE_MS) { msA += mA; msB += mB; }
            PA0 = fmaf(mA, fA.x, PA0); PA1 = fmaf(mA, fA.y, PA1); PA2 = fmaf(mA, fA.z, PA2);
            PB0 = fmaf(mB, fB.x, PB0); PB1 = fmaf(mB, fB.y, PB1); PB2 = fmaf(mB, fB.z, PB2);
        }

        // ---- fold wp and reduce across all 64 lanes ----
        float vA0 = PA0 * wp0, vA1 = PA1 * wp1, vA2 = PA2 * wp2;
        float vB0 = PB0 * wp0, vB1 = PB1 * wp1, vB2 = PB2 * wp2;
#pragma unroll
        for (int off = 32; off > 0; off >>= 1) {
            vA0 += __shfl_xor(vA0, off); vA1 += __shfl_xor(vA1, off); vA2 += __shfl_xor(vA2, off);
            vB0 += __shfl_xor(vB0, off); vB1 += __shfl_xor(vB1, off); vB2 += __shfl_xor(vB2, off);
        }
        if (WRITE_MS) {
            msA += __shfl_xor(msA, 32);        // combine the two j-halves per k
            msB += __shfl_xor(msB, 32);
        }
        __syncthreads();                       // SxL consumed; wacc reusable
        if (lane == 0) {
            wacc[wid][0] = vA0; wacc[wid][1] = vA1; wacc[wid][2] = vA2;
            wacc[wid][3] = vB0; wacc[wid][4] = vB1; wacc[wid][5] = vB2;
        }
        if (WRITE_MS && lane < 32) { msAl[wid][k] = msA; msBl[wid][k] = msB; }
        __syncthreads();                       // epilogue data ready

        if (tid == 0) {
            const float bp0 = bpos[0], bp1 = bpos[1], bp2 = bpos[2];
            float aA0 = wacc[0][0] + wacc[1][0] + wacc[2][0] + wacc[3][0];
            float aA1 = wacc[0][1] + wacc[1][1] + wacc[2][1] + wacc[3][1];
            float aA2 = wacc[0][2] + wacc[1][2] + wacc[2][2] + wacc[3][2];
            float aB0 = wacc[0][3] + wacc[1][3] + wacc[2][3] + wacc[3][3];
            float aB1 = wacc[0][4] + wacc[1][4] + wacc[2][4] + wacc[3][4];
            float aB2 = wacc[0][5] + wacc[1][5] + wacc[2][5] + wacc[3][5];
            const float inv = 1.0f / 1023.0f;
            xout[iA * 3 + 0] = xiA0 + (aA0 + bp0 * (SxL[0] - (float)N * xiA0)) * inv;
            xout[iA * 3 + 1] = xiA1 + (aA1 + bp1 * (SxL[1] - (float)N * xiA1)) * inv;
            xout[iA * 3 + 2] = xiA2 + (aA2 + bp2 * (SxL[2] - (float)N * xiA2)) * inv;
            xout[iB * 3 + 0] = xiB0 + (aB0 + bp0 * (SxL[0] - (float)N * xiB0)) * inv;
            xout[iB * 3 + 1] = xiB1 + (aB1 + bp1 * (SxL[1] - (float)N * xiB1)) * inv;
            xout[iB * 3 + 2] = xiB2 + (aB2 + bp2 * (SxL[2] - (float)N * xiB2)) * inv;
        }
        if (WRITE_MS) {
            if (tid < MD) {
                float s = msAl[0][tid] + msAl[1][tid] + msAl[2][tid] + msAl[3][tid];
                s -= fmaxf(Aap[iA * MD + tid] + Bbp[iA * MD + tid], 0.f);  // diag (d2=0)
                msout[iA * MD + tid] = s;
            } else if (tid < 2 * MD) {
                const int kk = tid - MD;
                float s = msBl[0][kk] + msBl[1][kk] + msBl[2][kk] + msBl[3][kk];
                s -= fmaxf(Aap[iB * MD + kk] + Bbp[iB * MD + kk], 0.f);
                msout[iB * MD + kk] = s;
            }
        }
        __syncthreads();                       // before rd tables are re-staged
    }
}

// ---------------------------------------------------------------------------
// Single cooperative kernel: 4 phases, 3 grid syncs, 1 launch.
// ---------------------------------------------------------------------------
__global__ __launch_bounds__(BLK, 2) void k_egnn(Params p)
{
    cg::grid_group grid = cg::this_grid();
    const int tid = threadIdx.x;
    const int bid = blockIdx.x;
    const int G   = gridDim.x;

    __shared__ float4 rd[2 * N];        // 32 KB: rdA | rdB, also phase-0/2 scratch
    __shared__ float  wacc[4][8];
    __shared__ float  msAl[4][MD];
    __shared__ float  msBl[4][MD];
    __shared__ float  SxL[3];
    float4* rdA = rd;
    float4* rdB = rd + N;
    float*  scr = (float*)rd;           // 8192 floats of scratch

    // ========== P0: h0 = feat + posenc; A1/B1 projections (4 rows/chunk) =====
    for (int chunk = bid; chunk < N / 4; chunk += G) {
        const int n0 = chunk * 4;
        for (int u = tid; u < MD * WROW; u += BLK) scr[u] = p.w_msg1[u];  // 4128
        float* hrow = scr + 4160;
        {
            const int n = n0 + (tid >> 6), d = tid & 63;
            const float div = expf((float)(d & ~1) * (-9.210340371976184f / 64.0f));
            const float ang = (float)n * div;
            const float pe  = (d & 1) ? cosf(ang) : sinf(ang);
            const float hv  = p.feat[n * HD + d] + pe;
            p.h0[n * HD + d] = hv;
            hrow[tid] = hv;
        }
        __syncthreads();
        if (tid < 4 * MD) {
            const int nl = tid >> 5, m = tid & 31;
            const float* wa = scr + m * WROW;        // stride 129: conflict-free
            const float* hr = hrow + nl * HD;
            float sa = 0.f, sb = p.b_msg1[m];
#pragma unroll
            for (int c = 0; c < HD; c++) {
                const float hv = hr[c];
                sa = fmaf(hv, wa[c], sa);
                sb = fmaf(hv, wa[HD + c], sb);
            }
            const int n = n0 + nl;
            p.A1[n * MD + m] = sa;
            p.B1[n * MD + m] = sb;
        }
        __syncthreads();
    }
    grid.sync();

    // ========== P1: pair layer 1 -> x1, ms1 =================================
    pair_phase<1>(p, p.pos, p.A1, p.B1, p.w_msg1, p.w_pos1, p.b_pos1,
                  p.x1, p.ms1, rdA, rdB, wacc, msAl, msBl, SxL);
    grid.sync();

    // ========== P2: h1 = relu([h0, ms1] @ wf.T + bf); A2/B2 =================
    for (int chunk = bid; chunk < N / 4; chunk += G) {
        const int n0 = chunk * 4;
        float* wbig = scr;                  // 64 rows, padded stride 97 -> 6208
        float* h0r  = scr + 6208;           // 256
        float* msr  = scr + 6464;           // 128
        float* h1r  = scr + 6592;           // 256 (end 6848 < 8192)
        for (int u = tid; u < HD * (HD + MD); u += BLK) {
            const int o = u / (HD + MD), c = u - o * (HD + MD);
            wbig[o * 97 + c] = p.w_feat1[u];
        }
        h0r[tid] = p.h0[n0 * HD + tid];
        if (tid < 4 * MD) msr[tid] = p.ms1[n0 * MD + tid];
        __syncthreads();
        {
            const int nl = tid >> 6, o = tid & 63;
            const float* w  = wbig + o * 97;         // stride 97: conflict-free
            const float* hh = h0r + nl * HD;
            const float* mm = msr + nl * MD;
            float s = p.b_feat1[o];
#pragma unroll
            for (int c = 0; c < HD; c++) s = fmaf(hh[c], w[c], s);
#pragma unroll
            for (int c = 0; c < MD; c++) s = fmaf(mm[c], w[HD + c], s);
            h1r[tid] = fmaxf(s, 0.f);
        }
        __syncthreads();
        for (int u = tid; u < MD * WROW; u += BLK) wbig[u] = p.w_msg2[u];  // 4128 < 6208
        __syncthreads();
        if (tid < 4 * MD) {
            const int nl = tid >> 5, m = tid & 31;
            const float* wa = wbig + m * WROW;
            const float* hr = h1r + nl * HD;
            float sa = 0.f, sb = p.b_msg2[m];
#pragma unroll
            for (int c = 0; c < HD; c++) {
                const float hv = hr[c];
                sa = fmaf(hv, wa[c], sa);
                sb = fmaf(hv, wa[HD + c], sb);
            }
            const int n = n0 + nl;
            p.A2[n * MD + m] = sa;
            p.B2[n * MD + m] = sb;
        }
        __syncthreads();
    }
    grid.sync();

    // ========== P3: pair layer 2 -> out (positions only) ====================
    pair_phase<0>(p, p.x1, p.A2, p.B2, p.w_msg2, p.w_pos2, p.b_pos2,
                  p.out, nullptr, rdA, rdB, wacc, msAl, msBl, SxL);
}

// ---------------------------------------------------------------------------
extern "C" void kernel_launch(void* const* d_in, const int* in_sizes, int n_in,
                              void* d_out, int out_size, void* d_ws, size_t ws_size,
                              hipStream_t stream)
{
    float* ws = (float*)d_ws;
    Params prm;
    prm.pos    = (const float*)d_in[0];
    prm.feat   = (const float*)d_in[1];
    prm.w_msg1 = (const float*)d_in[3];
    prm.b_msg1 = (const float*)d_in[4];
    prm.w_pos1 = (const float*)d_in[5];
    prm.b_pos1 = (const float*)d_in[6];
    prm.w_feat1= (const float*)d_in[7];
    prm.b_feat1= (const float*)d_in[8];
    prm.w_msg2 = (const float*)d_in[9];
    prm.b_msg2 = (const float*)d_in[10];
    prm.w_pos2 = (const float*)d_in[11];
    prm.b_pos2 = (const float*)d_in[12];
    prm.h0  = ws;                    // 65536
    prm.A1  = prm.h0  + N * HD;      // 32768
    prm.B1  = prm.A1  + N * MD;
    prm.x1  = prm.B1  + N * MD;      // 4096 (padded)
    prm.ms1 = prm.x1  + N * 4;
    prm.A2  = prm.ms1 + N * MD;
    prm.B2  = prm.A2  + N * MD;
    prm.out = (float*)d_out;

    int nb = 0;
    if (hipOccupancyMaxActiveBlocksPerMultiprocessor(&nb, (const void*)k_egnn, BLK, 0)
            != hipSuccess || nb < 1)
        nb = 2;
    int G = nb * 256;                // 256 CUs on MI355X
    if (G > 512) G = 512;

    void* args[] = { &prm };
    hipLaunchCooperativeKernel((const void*)k_egnn, dim3(G), dim3(BLK), args, 0, stream);
}

// Round 6
// 153.638 us; speedup vs baseline: 1.1714x; 1.1714x over previous
//
#include <hip/hip_runtime.h>

#define N   1024
#define HD  64
#define MD  32
#define BLK 256
#define WROW (2 * HD + 1)   // 129, w_msg row stride

struct Params {
    const float* pos;
    const float* feat;
    const float* w_msg1; const float* b_msg1; const float* w_pos1; const float* b_pos1;
    const float* w_feat1; const float* b_feat1;
    const float* w_msg2; const float* b_msg2; const float* w_pos2; const float* b_pos2;
    float* h0; float* A1; float* B1; float* x1; float* ms1; float* A2; float* B2;
    float* out;
    unsigned* cnt;          // grid-barrier counter (zeroed每 launch via memset node)
};

// ---------------------------------------------------------------------------
// Hand-rolled grid barrier (replaces cg::grid.sync, which measured ~50us each).
// Monotonic epoch counter: after barrier e, *cnt == gridDim.x * e.
// Leader: release-add (flushes this block's stores to device scope), relaxed
// spin (no per-poll cache invalidate), one acquire fence on exit.
// Safe only under cooperative launch (all blocks co-resident).
// ---------------------------------------------------------------------------
__device__ __forceinline__ void grid_bar(unsigned* cnt, unsigned epoch)
{
    __syncthreads();                       // drains vmcnt: block's stores in L2
    if (threadIdx.x == 0) {
        const unsigned target = gridDim.x * epoch;
        __hip_atomic_fetch_add(cnt, 1u, __ATOMIC_RELEASE, __HIP_MEMORY_SCOPE_AGENT);
        while (__hip_atomic_load(cnt, __ATOMIC_RELAXED, __HIP_MEMORY_SCOPE_AGENT) < target)
            __builtin_amdgcn_s_sleep(2);
        __threadfence();                   // acquire: invalidate stale L1/L2
    }
    __syncthreads();
}

// ---------------------------------------------------------------------------
// Pair phase: grid-stride over row-pairs (iA, iB = iA + N/2). Block = 256 thr.
// Lane mapping in main loop: jbase = tid>>5 (8 j-slots/iter), k = tid&31.
// Per lane: m = relu(A[j][k] + Bi[k] + d2*wd[k]); P_c += m * r_c  (wp folded
// at the end); msum_k accumulated per-lane (layer 1 only).
// x_out[i] = x[i] + (S_k wp_ck P_ck + bp_c (Sx_c - N x_ic)) / (N-1)
// ---------------------------------------------------------------------------
template<int WRITE_MS>
__device__ void pair_phase(const float* __restrict__ xsrc,
                           const float* __restrict__ Aap,
                           const float* __restrict__ Bbp,
                           const float* __restrict__ wmsg,
                           const float* __restrict__ wpos,
                           const float* __restrict__ bpos,
                           float* __restrict__ xout,
                           float* __restrict__ msout,
                           float4* rdA, float4* rdB,
                           float (*wacc)[8], float (*msAl)[MD], float (*msBl)[MD],
                           float* SxL)
{
    const int tid  = threadIdx.x;
    const int bid  = blockIdx.x;
    const int G    = gridDim.x;
    const int wid  = tid >> 6;
    const int lane = tid & 63;
    const int k    = tid & 31;

    for (int i0 = bid; i0 < N / 2; i0 += G) {
        const int iA = i0, iB = i0 + N / 2;
        const float xiA0 = xsrc[iA * 3 + 0], xiA1 = xsrc[iA * 3 + 1], xiA2 = xsrc[iA * 3 + 2];
        const float xiB0 = xsrc[iB * 3 + 0], xiB1 = xsrc[iB * 3 + 1], xiB2 = xsrc[iB * 3 + 2];

        // ---- stage r/d2 tables for both rows; accumulate column-sum of x ----
        float sx0 = 0.f, sx1 = 0.f, sx2 = 0.f;
#pragma unroll
        for (int q = 0; q < N / BLK; q++) {
            const int j = q * BLK + tid;
            const float xj0 = xsrc[j * 3 + 0];
            const float xj1 = xsrc[j * 3 + 1];
            const float xj2 = xsrc[j * 3 + 2];
            sx0 += xj0; sx1 += xj1; sx2 += xj2;
            float r0 = xj0 - xiA0, r1 = xj1 - xiA1, r2 = xj2 - xiA2;
            rdA[j] = make_float4(r0, r1, r2, fmaf(r0, r0, fmaf(r1, r1, r2 * r2)));
            r0 = xj0 - xiB0; r1 = xj1 - xiB1; r2 = xj2 - xiB2;
            rdB[j] = make_float4(r0, r1, r2, fmaf(r0, r0, fmaf(r1, r1, r2 * r2)));
        }
#pragma unroll
        for (int off = 32; off > 0; off >>= 1) {
            sx0 += __shfl_xor(sx0, off);
            sx1 += __shfl_xor(sx1, off);
            sx2 += __shfl_xor(sx2, off);
        }
        if (lane == 0) { wacc[wid][0] = sx0; wacc[wid][1] = sx1; wacc[wid][2] = sx2; }
        __syncthreads();                       // rd tables + sx partials ready
        if (tid == 0) {
            SxL[0] = wacc[0][0] + wacc[1][0] + wacc[2][0] + wacc[3][0];
            SxL[1] = wacc[0][1] + wacc[1][1] + wacc[2][1] + wacc[3][1];
            SxL[2] = wacc[0][2] + wacc[1][2] + wacc[2][2] + wacc[3][2];
        }

        // ---- per-lane (dim-k) weights: 6 VGPRs instead of 160 ----
        const float BiA = Bbp[iA * MD + k];
        const float BiB = Bbp[iB * MD + k];
        const float wd  = wmsg[k * WROW + 2 * HD];
        const float wp0 = wpos[k], wp1 = wpos[MD + k], wp2 = wpos[2 * MD + k];

        float PA0 = 0.f, PA1 = 0.f, PA2 = 0.f;
        float PB0 = 0.f, PB1 = 0.f, PB2 = 0.f;
        float msA = 0.f, msB = 0.f;
        const int jbase = tid >> 5;            // 0..7

#pragma unroll 4
        for (int it = 0; it < N / 8; it++) {
            const int j = it * 8 + jbase;
            const float a = Aap[j * MD + k];
            const float4 fA = rdA[j];          // broadcast within 32-lane group
            const float4 fB = rdB[j];
            const float mA = fmaxf(fmaf(fA.w, wd, a + BiA), 0.f);
            const float mB = fmaxf(fmaf(fB.w, wd, a + BiB), 0.f);
            if (WRITE_MS) { msA += mA; msB += mB; }
            PA0 = fmaf(mA, fA.x, PA0); PA1 = fmaf(mA, fA.y, PA1); PA2 = fmaf(mA, fA.z, PA2);
            PB0 = fmaf(mB, fB.x, PB0); PB1 = fmaf(mB, fB.y, PB1); PB2 = fmaf(mB, fB.z, PB2);
        }

        // ---- fold wp and reduce across all 64 lanes ----
        float vA0 = PA0 * wp0, vA1 = PA1 * wp1, vA2 = PA2 * wp2;
        float vB0 = PB0 * wp0, vB1 = PB1 * wp1, vB2 = PB2 * wp2;
#pragma unroll
        for (int off = 32; off > 0; off >>= 1) {
            vA0 += __shfl_xor(vA0, off); vA1 += __shfl_xor(vA1, off); vA2 += __shfl_xor(vA2, off);
            vB0 += __shfl_xor(vB0, off); vB1 += __shfl_xor(vB1, off); vB2 += __shfl_xor(vB2, off);
        }
        if (WRITE_MS) {
            msA += __shfl_xor(msA, 32);        // combine the two j-halves per k
            msB += __shfl_xor(msB, 32);
        }
        __syncthreads();                       // SxL consumed; wacc reusable
        if (lane == 0) {
            wacc[wid][0] = vA0; wacc[wid][1] = vA1; wacc[wid][2] = vA2;
            wacc[wid][3] = vB0; wacc[wid][4] = vB1; wacc[wid][5] = vB2;
        }
        if (WRITE_MS && lane < 32) { msAl[wid][k] = msA; msBl[wid][k] = msB; }
        __syncthreads();                       // epilogue data ready

        if (tid == 0) {
            const float bp0 = bpos[0], bp1 = bpos[1], bp2 = bpos[2];
            float aA0 = wacc[0][0] + wacc[1][0] + wacc[2][0] + wacc[3][0];
            float aA1 = wacc[0][1] + wacc[1][1] + wacc[2][1] + wacc[3][1];
            float aA2 = wacc[0][2] + wacc[1][2] + wacc[2][2] + wacc[3][2];
            float aB0 = wacc[0][3] + wacc[1][3] + wacc[2][3] + wacc[3][3];
            float aB1 = wacc[0][4] + wacc[1][4] + wacc[2][4] + wacc[3][4];
            float aB2 = wacc[0][5] + wacc[1][5] + wacc[2][5] + wacc[3][5];
            const float inv = 1.0f / 1023.0f;
            xout[iA * 3 + 0] = xiA0 + (aA0 + bp0 * (SxL[0] - (float)N * xiA0)) * inv;
            xout[iA * 3 + 1] = xiA1 + (aA1 + bp1 * (SxL[1] - (float)N * xiA1)) * inv;
            xout[iA * 3 + 2] = xiA2 + (aA2 + bp2 * (SxL[2] - (float)N * xiA2)) * inv;
            xout[iB * 3 + 0] = xiB0 + (aB0 + bp0 * (SxL[0] - (float)N * xiB0)) * inv;
            xout[iB * 3 + 1] = xiB1 + (aB1 + bp1 * (SxL[1] - (float)N * xiB1)) * inv;
            xout[iB * 3 + 2] = xiB2 + (aB2 + bp2 * (SxL[2] - (float)N * xiB2)) * inv;
        }
        if (WRITE_MS) {
            if (tid < MD) {
                float s = msAl[0][tid] + msAl[1][tid] + msAl[2][tid] + msAl[3][tid];
                s -= fmaxf(Aap[iA * MD + tid] + Bbp[iA * MD + tid], 0.f);  // diag (d2=0)
                msout[iA * MD + tid] = s;
            } else if (tid < 2 * MD) {
                const int kk = tid - MD;
                float s = msBl[0][kk] + msBl[1][kk] + msBl[2][kk] + msBl[3][kk];
                s -= fmaxf(Aap[iB * MD + kk] + Bbp[iB * MD + kk], 0.f);
                msout[iB * MD + kk] = s;
            }
        }
        __syncthreads();                       // before rd tables are re-staged
    }
}

// ---------------------------------------------------------------------------
// Single cooperative kernel: 4 phases, 3 hand-rolled grid barriers, 1 launch.
// ---------------------------------------------------------------------------
__global__ __launch_bounds__(BLK, 2) void k_egnn(Params p)
{
    const int tid = threadIdx.x;
    const int bid = blockIdx.x;
    const int G   = gridDim.x;

    __shared__ float4 rd[2 * N];        // 32 KB: rdA | rdB, also phase-0/2 scratch
    __shared__ float  wacc[4][8];
    __shared__ float  msAl[4][MD];
    __shared__ float  msBl[4][MD];
    __shared__ float  SxL[3];
    float4* rdA = rd;
    float4* rdB = rd + N;
    float*  scr = (float*)rd;           // 8192 floats of scratch

    // ========== P0: h0 = feat + posenc; A1/B1 projections (4 rows/chunk) =====
    for (int chunk = bid; chunk < N / 4; chunk += G) {
        const int n0 = chunk * 4;
        for (int u = tid; u < MD * WROW; u += BLK) scr[u] = p.w_msg1[u];  // 4128
        float* hrow = scr + 4160;
        {
            const int n = n0 + (tid >> 6), d = tid & 63;
            const float div = expf((float)(d & ~1) * (-9.210340371976184f / 64.0f));
            const float ang = (float)n * div;
            const float pe  = (d & 1) ? cosf(ang) : sinf(ang);
            const float hv  = p.feat[n * HD + d] + pe;
            p.h0[n * HD + d] = hv;
            hrow[tid] = hv;
        }
        __syncthreads();
        if (tid < 4 * MD) {
            const int nl = tid >> 5, m = tid & 31;
            const float* wa = scr + m * WROW;        // stride 129: conflict-free
            const float* hr = hrow + nl * HD;
            float sa = 0.f, sb = p.b_msg1[m];
#pragma unroll
            for (int c = 0; c < HD; c++) {
                const float hv = hr[c];
                sa = fmaf(hv, wa[c], sa);
                sb = fmaf(hv, wa[HD + c], sb);
            }
            const int n = n0 + nl;
            p.A1[n * MD + m] = sa;
            p.B1[n * MD + m] = sb;
        }
        __syncthreads();
    }
    grid_bar(p.cnt, 1);

    // ========== P1: pair layer 1 -> x1, ms1 =================================
    pair_phase<1>(p.pos, p.A1, p.B1, p.w_msg1, p.w_pos1, p.b_pos1,
                  p.x1, p.ms1, rdA, rdB, wacc, msAl, msBl, SxL);
    grid_bar(p.cnt, 2);

    // ========== P2: h1 = relu([h0, ms1] @ wf.T + bf); A2/B2 =================
    for (int chunk = bid; chunk < N / 4; chunk += G) {
        const int n0 = chunk * 4;
        float* wbig = scr;                  // 64 rows, padded stride 97 -> 6208
        float* h0r  = scr + 6208;           // 256
        float* msr  = scr + 6464;           // 128
        float* h1r  = scr + 6592;           // 256 (end 6848 < 8192)
        for (int u = tid; u < HD * (HD + MD); u += BLK) {
            const int o = u / (HD + MD), c = u - o * (HD + MD);
            wbig[o * 97 + c] = p.w_feat1[u];
        }
        h0r[tid] = p.h0[n0 * HD + tid];
        if (tid < 4 * MD) msr[tid] = p.ms1[n0 * MD + tid];
        __syncthreads();
        {
            const int nl = tid >> 6, o = tid & 63;
            const float* w  = wbig + o * 97;         // stride 97: conflict-free
            const float* hh = h0r + nl * HD;
            const float* mm = msr + nl * MD;
            float s = p.b_feat1[o];
#pragma unroll
            for (int c = 0; c < HD; c++) s = fmaf(hh[c], w[c], s);
#pragma unroll
            for (int c = 0; c < MD; c++) s = fmaf(mm[c], w[HD + c], s);
            h1r[tid] = fmaxf(s, 0.f);
        }
        __syncthreads();
        for (int u = tid; u < MD * WROW; u += BLK) wbig[u] = p.w_msg2[u];  // 4128 < 6208
        __syncthreads();
        if (tid < 4 * MD) {
            const int nl = tid >> 5, m = tid & 31;
            const float* wa = wbig + m * WROW;
            const float* hr = h1r + nl * HD;
            float sa = 0.f, sb = p.b_msg2[m];
#pragma unroll
            for (int c = 0; c < HD; c++) {
                const float hv = hr[c];
                sa = fmaf(hv, wa[c], sa);
                sb = fmaf(hv, wa[HD + c], sb);
            }
            const int n = n0 + nl;
            p.A2[n * MD + m] = sa;
            p.B2[n * MD + m] = sb;
        }
        __syncthreads();
    }
    grid_bar(p.cnt, 3);

    // ========== P3: pair layer 2 -> out (positions only) ====================
    pair_phase<0>(p.x1, p.A2, p.B2, p.w_msg2, p.w_pos2, p.b_pos2,
                  p.out, nullptr, rdA, rdB, wacc, msAl, msBl, SxL);
}

// ---------------------------------------------------------------------------
extern "C" void kernel_launch(void* const* d_in, const int* in_sizes, int n_in,
                              void* d_out, int out_size, void* d_ws, size_t ws_size,
                              hipStream_t stream)
{
    float* ws = (float*)d_ws;
    Params prm;
    prm.pos    = (const float*)d_in[0];
    prm.feat   = (const float*)d_in[1];
    prm.w_msg1 = (const float*)d_in[3];
    prm.b_msg1 = (const float*)d_in[4];
    prm.w_pos1 = (const float*)d_in[5];
    prm.b_pos1 = (const float*)d_in[6];
    prm.w_feat1= (const float*)d_in[7];
    prm.b_feat1= (const float*)d_in[8];
    prm.w_msg2 = (const float*)d_in[9];
    prm.b_msg2 = (const float*)d_in[10];
    prm.w_pos2 = (const float*)d_in[11];
    prm.b_pos2 = (const float*)d_in[12];
    prm.h0  = ws;                    // 65536
    prm.A1  = prm.h0  + N * HD;      // 32768
    prm.B1  = prm.A1  + N * MD;
    prm.x1  = prm.B1  + N * MD;      // 4096 (padded)
    prm.ms1 = prm.x1  + N * 4;
    prm.A2  = prm.ms1 + N * MD;
    prm.B2  = prm.A2  + N * MD;
    prm.out = (float*)d_out;
    prm.cnt = (unsigned*)((char*)d_ws + (32u << 20));   // +32 MiB, far from data

    // zero the barrier counter every call (memset node in the graph)
    hipMemsetAsync((void*)prm.cnt, 0, 64, stream);

    int nb = 0;
    if (hipOccupancyMaxActiveBlocksPerMultiprocessor(&nb, (const void*)k_egnn, BLK, 0)
            != hipSuccess || nb < 1)
        nb = 2;
    int G = nb * 256;                // 256 CUs on MI355X
    if (G > 512) G = 512;

    void* args[] = { &prm };
    hipLaunchCooperativeKernel((const void*)k_egnn, dim3(G), dim3(BLK), args, 0, stream);
}

// Round 7
// 43.798 us; speedup vs baseline: 4.1090x; 3.5079x over previous
//
#include <hip/hip_runtime.h>

#define N   1024
#define HD  64
#define MD  32
#define BLK 256
#define WROW (2 * HD + 1)   // 129, w_msg row stride

// ---------------------------------------------------------------------------
// P0: h0 = feat + posenc; A1/B1 projections. One block per 4 rows.
// ---------------------------------------------------------------------------
__global__ __launch_bounds__(BLK) void k_p0(const float* __restrict__ feat,
                                            const float* __restrict__ wmsg,
                                            const float* __restrict__ bmsg,
                                            float* __restrict__ h0,
                                            float* __restrict__ A,
                                            float* __restrict__ Bb)
{
    __shared__ float scr[4160 + 4 * HD];
    const int tid = threadIdx.x;
    const int n0  = blockIdx.x * 4;

    for (int u = tid; u < MD * WROW; u += BLK) scr[u] = wmsg[u];   // 4128 floats
    float* hrow = scr + 4160;
    {
        const int n = n0 + (tid >> 6), d = tid & 63;
        const float div = expf((float)(d & ~1) * (-9.210340371976184f / 64.0f));
        const float ang = (float)n * div;
        const float pe  = (d & 1) ? cosf(ang) : sinf(ang);
        const float hv  = feat[n * HD + d] + pe;
        h0[n * HD + d] = hv;
        hrow[tid] = hv;
    }
    __syncthreads();
    if (tid < 4 * MD) {
        const int nl = tid >> 5, m = tid & 31;
        const float* wa = scr + m * WROW;          // stride 129: conflict-free
        const float* hr = hrow + nl * HD;
        float sa = 0.f, sb = bmsg[m];
#pragma unroll
        for (int c = 0; c < HD; c++) {
            const float hv = hr[c];
            sa = fmaf(hv, wa[c], sa);
            sb = fmaf(hv, wa[HD + c], sb);
        }
        const int n = n0 + nl;
        A[n * MD + m]  = sa;
        Bb[n * MD + m] = sb;
    }
}

// ---------------------------------------------------------------------------
// P2: h1 = relu([h0, ms1] @ wf.T + bf); A2/B2 projections. One block per 4 rows.
// ---------------------------------------------------------------------------
__global__ __launch_bounds__(BLK) void k_p2(const float* __restrict__ h0,
                                            const float* __restrict__ ms1,
                                            const float* __restrict__ wf,
                                            const float* __restrict__ bf,
                                            const float* __restrict__ wmsg,
                                            const float* __restrict__ bmsg,
                                            float* __restrict__ A,
                                            float* __restrict__ Bb)
{
    __shared__ float scr[6848];
    const int tid = threadIdx.x;
    const int n0  = blockIdx.x * 4;

    float* wbig = scr;                  // 64 rows, padded stride 97 -> 6208
    float* h0r  = scr + 6208;           // 256
    float* msr  = scr + 6464;           // 128
    float* h1r  = scr + 6592;           // 256 (end 6848)
    for (int u = tid; u < HD * (HD + MD); u += BLK) {
        const int o = u / (HD + MD), c = u - o * (HD + MD);
        wbig[o * 97 + c] = wf[u];
    }
    h0r[tid] = h0[n0 * HD + tid];
    if (tid < 4 * MD) msr[tid] = ms1[n0 * MD + tid];
    __syncthreads();
    {
        const int nl = tid >> 6, o = tid & 63;
        const float* w  = wbig + o * 97;           // stride 97: conflict-free
        const float* hh = h0r + nl * HD;
        const float* mm = msr + nl * MD;
        float s = bf[o];
#pragma unroll
        for (int c = 0; c < HD; c++) s = fmaf(hh[c], w[c], s);
#pragma unroll
        for (int c = 0; c < MD; c++) s = fmaf(mm[c], w[HD + c], s);
        h1r[tid] = fmaxf(s, 0.f);
    }
    __syncthreads();
    for (int u = tid; u < MD * WROW; u += BLK) wbig[u] = wmsg[u];   // 4128 < 6208
    __syncthreads();
    if (tid < 4 * MD) {
        const int nl = tid >> 5, m = tid & 31;
        const float* wa = wbig + m * WROW;
        const float* hr = h1r + nl * HD;
        float sa = 0.f, sb = bmsg[m];
#pragma unroll
        for (int c = 0; c < HD; c++) {
            const float hv = hr[c];
            sa = fmaf(hv, wa[c], sa);
            sb = fmaf(hv, wa[HD + c], sb);
        }
        const int n = n0 + nl;
        A[n * MD + m]  = sa;
        Bb[n * MD + m] = sb;
    }
}

// ---------------------------------------------------------------------------
// Pair kernel: one block (256 thr) per row-pair (iA, iB = iA + N/2).
// Lane mapping in main loop: jbase = tid>>5 (8 j-slots/iter), k = tid&31.
// Per lane: m = relu(A[j][k] + Bi[k] + d2*wd[k]); P_c += m * r_c  (wp folded
// at the end); msum_k accumulated per-lane (layer 1 only).
// x_out[i] = x[i] + (S_k wp_ck P_ck + bp_c (Sx_c - N x_ic)) / (N-1)
// Diagonal j==i: r=0 kills the position term; msum corrected in the epilogue.
// ---------------------------------------------------------------------------
template<int WRITE_MS>
__global__ __launch_bounds__(BLK) void k_pair(
    const float* __restrict__ xsrc, const float* __restrict__ Aap,
    const float* __restrict__ Bbp, const float* __restrict__ wmsg,
    const float* __restrict__ wpos, const float* __restrict__ bpos,
    float* __restrict__ xout, float* __restrict__ msout)
{
    const int tid  = threadIdx.x;
    const int wid  = tid >> 6;
    const int lane = tid & 63;
    const int k    = tid & 31;

    __shared__ float4 rdA[N];           // 16 KB
    __shared__ float4 rdB[N];           // 16 KB
    __shared__ float  wacc[4][8];
    __shared__ float  msAl[4][MD];
    __shared__ float  msBl[4][MD];
    __shared__ float  SxL[3];

    const int iA = blockIdx.x, iB = blockIdx.x + N / 2;
    const float xiA0 = xsrc[iA * 3 + 0], xiA1 = xsrc[iA * 3 + 1], xiA2 = xsrc[iA * 3 + 2];
    const float xiB0 = xsrc[iB * 3 + 0], xiB1 = xsrc[iB * 3 + 1], xiB2 = xsrc[iB * 3 + 2];

    // ---- stage r/d2 tables for both rows; accumulate column-sum of x ----
    float sx0 = 0.f, sx1 = 0.f, sx2 = 0.f;
#pragma unroll
    for (int q = 0; q < N / BLK; q++) {
        const int j = q * BLK + tid;
        const float xj0 = xsrc[j * 3 + 0];
        const float xj1 = xsrc[j * 3 + 1];
        const float xj2 = xsrc[j * 3 + 2];
        sx0 += xj0; sx1 += xj1; sx2 += xj2;
        float r0 = xj0 - xiA0, r1 = xj1 - xiA1, r2 = xj2 - xiA2;
        rdA[j] = make_float4(r0, r1, r2, fmaf(r0, r0, fmaf(r1, r1, r2 * r2)));
        r0 = xj0 - xiB0; r1 = xj1 - xiB1; r2 = xj2 - xiB2;
        rdB[j] = make_float4(r0, r1, r2, fmaf(r0, r0, fmaf(r1, r1, r2 * r2)));
    }
#pragma unroll
    for (int off = 32; off > 0; off >>= 1) {
        sx0 += __shfl_xor(sx0, off);
        sx1 += __shfl_xor(sx1, off);
        sx2 += __shfl_xor(sx2, off);
    }
    if (lane == 0) { wacc[wid][0] = sx0; wacc[wid][1] = sx1; wacc[wid][2] = sx2; }
    __syncthreads();                       // rd tables + sx partials ready
    if (tid == 0) {
        SxL[0] = wacc[0][0] + wacc[1][0] + wacc[2][0] + wacc[3][0];
        SxL[1] = wacc[0][1] + wacc[1][1] + wacc[2][1] + wacc[3][1];
        SxL[2] = wacc[0][2] + wacc[1][2] + wacc[2][2] + wacc[3][2];
    }

    // ---- per-lane (dim-k) weights: 6 VGPRs instead of 160 ----
    const float BiA = Bbp[iA * MD + k];
    const float BiB = Bbp[iB * MD + k];
    const float wd  = wmsg[k * WROW + 2 * HD];
    const float wp0 = wpos[k], wp1 = wpos[MD + k], wp2 = wpos[2 * MD + k];

    float PA0 = 0.f, PA1 = 0.f, PA2 = 0.f;
    float PB0 = 0.f, PB1 = 0.f, PB2 = 0.f;
    float msA = 0.f, msB = 0.f;
    const int jbase = tid >> 5;            // 0..7

#pragma unroll 4
    for (int it = 0; it < N / 8; it++) {
        const int j = it * 8 + jbase;
        const float a = Aap[j * MD + k];   // coalesced 256B/wave from L2
        const float4 fA = rdA[j];          // broadcast within 32-lane group
        const float4 fB = rdB[j];
        const float mA = fmaxf(fmaf(fA.w, wd, a + BiA), 0.f);
        const float mB = fmaxf(fmaf(fB.w, wd, a + BiB), 0.f);
        if (WRITE_MS) { msA += mA; msB += mB; }
        PA0 = fmaf(mA, fA.x, PA0); PA1 = fmaf(mA, fA.y, PA1); PA2 = fmaf(mA, fA.z, PA2);
        PB0 = fmaf(mB, fB.x, PB0); PB1 = fmaf(mB, fB.y, PB1); PB2 = fmaf(mB, fB.z, PB2);
    }

    // ---- fold wp and reduce across all 64 lanes ----
    float vA0 = PA0 * wp0, vA1 = PA1 * wp1, vA2 = PA2 * wp2;
    float vB0 = PB0 * wp0, vB1 = PB1 * wp1, vB2 = PB2 * wp2;
#pragma unroll
    for (int off = 32; off > 0; off >>= 1) {
        vA0 += __shfl_xor(vA0, off); vA1 += __shfl_xor(vA1, off); vA2 += __shfl_xor(vA2, off);
        vB0 += __shfl_xor(vB0, off); vB1 += __shfl_xor(vB1, off); vB2 += __shfl_xor(vB2, off);
    }
    if (WRITE_MS) {
        msA += __shfl_xor(msA, 32);        // combine the two j-halves per k
        msB += __shfl_xor(msB, 32);
    }
    __syncthreads();                       // SxL consumed by nobody yet; safe reuse point
    if (lane == 0) {
        wacc[wid][0] = vA0; wacc[wid][1] = vA1; wacc[wid][2] = vA2;
        wacc[wid][3] = vB0; wacc[wid][4] = vB1; wacc[wid][5] = vB2;
    }
    if (WRITE_MS && lane < 32) { msAl[wid][k] = msA; msBl[wid][k] = msB; }
    __syncthreads();                       // epilogue data ready

    if (tid == 0) {
        const float bp0 = bpos[0], bp1 = bpos[1], bp2 = bpos[2];
        float aA0 = wacc[0][0] + wacc[1][0] + wacc[2][0] + wacc[3][0];
        float aA1 = wacc[0][1] + wacc[1][1] + wacc[2][1] + wacc[3][1];
        float aA2 = wacc[0][2] + wacc[1][2] + wacc[2][2] + wacc[3][2];
        float aB0 = wacc[0][3] + wacc[1][3] + wacc[2][3] + wacc[3][3];
        float aB1 = wacc[0][4] + wacc[1][4] + wacc[2][4] + wacc[3][4];
        float aB2 = wacc[0][5] + wacc[1][5] + wacc[2][5] + wacc[3][5];
        const float inv = 1.0f / 1023.0f;
        xout[iA * 3 + 0] = xiA0 + (aA0 + bp0 * (SxL[0] - (float)N * xiA0)) * inv;
        xout[iA * 3 + 1] = xiA1 + (aA1 + bp1 * (SxL[1] - (float)N * xiA1)) * inv;
        xout[iA * 3 + 2] = xiA2 + (aA2 + bp2 * (SxL[2] - (float)N * xiA2)) * inv;
        xout[iB * 3 + 0] = xiB0 + (aB0 + bp0 * (SxL[0] - (float)N * xiB0)) * inv;
        xout[iB * 3 + 1] = xiB1 + (aB1 + bp1 * (SxL[1] - (float)N * xiB1)) * inv;
        xout[iB * 3 + 2] = xiB2 + (aB2 + bp2 * (SxL[2] - (float)N * xiB2)) * inv;
    }
    if (WRITE_MS) {
        if (tid < MD) {
            float s = msAl[0][tid] + msAl[1][tid] + msAl[2][tid] + msAl[3][tid];
            s -= fmaxf(Aap[iA * MD + tid] + Bbp[iA * MD + tid], 0.f);  // diag (d2=0)
            msout[iA * MD + tid] = s;
        } else if (tid < 2 * MD) {
            const int kk = tid - MD;
            float s = msBl[0][kk] + msBl[1][kk] + msBl[2][kk] + msBl[3][kk];
            s -= fmaxf(Aap[iB * MD + kk] + Bbp[iB * MD + kk], 0.f);
            msout[iB * MD + kk] = s;
        }
    }
}

// ---------------------------------------------------------------------------
extern "C" void kernel_launch(void* const* d_in, const int* in_sizes, int n_in,
                              void* d_out, int out_size, void* d_ws, size_t ws_size,
                              hipStream_t stream)
{
    const float* pos     = (const float*)d_in[0];
    const float* feat    = (const float*)d_in[1];
    const float* w_msg1  = (const float*)d_in[3];
    const float* b_msg1  = (const float*)d_in[4];
    const float* w_pos1  = (const float*)d_in[5];
    const float* b_pos1  = (const float*)d_in[6];
    const float* w_feat1 = (const float*)d_in[7];
    const float* b_feat1 = (const float*)d_in[8];
    const float* w_msg2  = (const float*)d_in[9];
    const float* b_msg2  = (const float*)d_in[10];
    const float* w_pos2  = (const float*)d_in[11];
    const float* b_pos2  = (const float*)d_in[12];

    float* ws  = (float*)d_ws;
    float* h0  = ws;                 // N*HD
    float* A1  = h0  + N * HD;       // N*MD
    float* B1  = A1  + N * MD;
    float* x1  = B1  + N * MD;       // N*4 (padded)
    float* ms1 = x1  + N * 4;
    float* A2  = ms1 + N * MD;
    float* B2  = A2  + N * MD;

    k_p0<<<N / 4, BLK, 0, stream>>>(feat, w_msg1, b_msg1, h0, A1, B1);
    k_pair<1><<<N / 2, BLK, 0, stream>>>(pos, A1, B1, w_msg1, w_pos1, b_pos1, x1, ms1);
    k_p2<<<N / 4, BLK, 0, stream>>>(h0, ms1, w_feat1, b_feat1, w_msg2, b_msg2, A2, B2);
    k_pair<0><<<N / 2, BLK, 0, stream>>>(x1, A2, B2, w_msg2, w_pos2, b_pos2,
                                         (float*)d_out, nullptr);
}